// Round 14
// baseline (89.136 us; speedup 1.0000x reference)
//
#include <hip/hip_runtime.h>
#include <math.h>

#define LN_EPS 1e-5f
// B=2 L=512 D=512 H=8 DH=64 C=64 F=2048
// Sb layout (bf16): Sb[b,i,h,j] = Sb[((b*512+i)*8 + h)*512 + j]

typedef __bf16 bf16x8 __attribute__((ext_vector_type(8)));
typedef unsigned short u16x8 __attribute__((ext_vector_type(8)));
typedef float f32x4 __attribute__((ext_vector_type(4)));
typedef unsigned short ushort_t;
typedef unsigned int uint_t;

__device__ inline ushort_t f2bf(float f) {
  uint_t u = __float_as_uint(f);
  return (ushort_t)((u + 0x7FFFu + ((u >> 16) & 1u)) >> 16);
}
__device__ inline float bf2f(ushort_t b) {
  return __uint_as_float(((uint_t)b) << 16);
}
// v_cvt_pk_bf16_f32: D[15:0]=bf16(S0), D[31:16]=bf16(S1)
__device__ inline uint_t cvtpk(float lo, float hi) {
  uint_t r;
  asm("v_cvt_pk_bf16_f32 %0, %1, %2" : "=v"(r) : "v"(lo), "v"(hi));
  return r;
}
__device__ inline bf16x8 cvt8pk(float4 a, float4 b) {
  uint4 v;
  v.x = cvtpk(a.x, a.y); v.y = cvtpk(a.z, a.w);
  v.z = cvtpk(b.x, b.y); v.w = cvtpk(b.z, b.w);
  return __builtin_bit_cast(bf16x8, v);
}

// ---------------------------------------------------------------------------
// K1 "qw_conv": blocks 0..1023: qwb[b,i,h,c] (bf16, coalesced rel_w reads),
//   qb[b,i,h], and srcb row (src row already staged in LDS).
// blocks 1024..1151: convert w1->w1b, w2->w2b.
// ---------------------------------------------------------------------------
__global__ __launch_bounds__(256) void qw_conv_kernel(
    const float* __restrict__ src, const float* __restrict__ rel_w,
    const float* __restrict__ rel_b,
    const float* __restrict__ w1, const float* __restrict__ w2,
    ushort_t* __restrict__ qwb, float* __restrict__ qb,
    ushort_t* __restrict__ srcb, ushort_t* __restrict__ w1b,
    ushort_t* __restrict__ w2b)
{
  const int tid = threadIdx.x;
  if (blockIdx.x >= 1024) {
    const int cb = blockIdx.x - 1024;          // 0..127
    const int tg = cb*256 + tid;               // 0..32767
    for (int it = tg; it < 131072; it += 32768) {
      const int i = it*8;
      const float4 a = *(const float4*)(w1 + i);
      const float4 b = *(const float4*)(w1 + i + 4);
      uint4 v;
      v.x = cvtpk(a.x, a.y); v.y = cvtpk(a.z, a.w);
      v.z = cvtpk(b.x, b.y); v.w = cvtpk(b.z, b.w);
      *(uint4*)(w1b + i) = v;
    }
    for (int it = tg; it < 131072; it += 32768) {
      const int i = it*8;
      const float4 a = *(const float4*)(w2 + i);
      const float4 b = *(const float4*)(w2 + i + 4);
      uint4 v;
      v.x = cvtpk(a.x, a.y); v.y = cvtpk(a.z, a.w);
      v.z = cvtpk(b.x, b.y); v.w = cvtpk(b.z, b.w);
      *(uint4*)(w2b + i) = v;
    }
    return;
  }

  const int bi = blockIdx.x;     // b*512 + i
  __shared__ float q_sh[512];
  q_sh[tid]       = src[bi*512 + tid];
  q_sh[tid + 256] = src[bi*512 + tid + 256];
  __syncthreads();
  // srcb from LDS
  {
    const float a = q_sh[2*tid], b = q_sh[2*tid + 1];
    *(uint_t*)&srcb[(size_t)bi*512 + 2*tid] = cvtpk(a, b);
  }
  // qw: wave w owns heads {2w, 2w+1}; lane = c. rel_w reads coalesced per d.
  const int lane = tid & 63, w = tid >> 6;
  #pragma unroll
  for (int hh = 0; hh < 2; ++hh) {
    const int h = w*2 + hh;
    const float* rwh = rel_w + h*4096;      // rel_w[(h*64+d)*64 + c]
    float s = 0.f;
    #pragma unroll 8
    for (int d = 0; d < 64; ++d)
      s = fmaf(q_sh[h*64 + d], rwh[d*64 + lane], s);
    qwb[(size_t)bi*512 + h*64 + lane] = f2bf(s);
  }
  if (tid < 8) {
    float s = 0.f;
    for (int d = 0; d < 64; ++d) s = fmaf(q_sh[tid*64+d], rel_b[tid*64+d], s);
    qb[bi*8 + tid] = s;
  }
}

// ---------------------------------------------------------------------------
// K2 "rel_stream": pure 134MB stream, 8 waves/block:
//   Sb[b,i,h,j] = bf16( sum_c RF[b,i,j,c]*qw[h,c] + qb[h] ) via MFMA.
// ---------------------------------------------------------------------------
__global__ __launch_bounds__(512) void rel_stream_kernel(
    const float* __restrict__ relf, const ushort_t* __restrict__ qwb,
    const float* __restrict__ qb, ushort_t* __restrict__ Sb)
{
  const int bi = blockIdx.x;           // b*512 + i
  const int tid = threadIdx.x;
  const int lane = tid & 63, w = tid >> 6;   // w 0..7
  const int hl = lane & 15;          // D col (head), valid < 8
  const int kc = lane >> 4;          // k-chunk 0..3
  const int h  = hl & 7;

  const bf16x8 b0 = *(const bf16x8*)&qwb[(size_t)bi*512 + h*64 + kc*8];
  const bf16x8 b1 = *(const bf16x8*)&qwb[(size_t)bi*512 + h*64 + 32 + kc*8];
  const float qbv = qb[bi*8 + h];
  ushort_t* Sp = Sb + ((size_t)bi*8 + h)*512;

  #pragma unroll
  for (int t = 0; t < 4; ++t) {
    const int j0 = (t*8 + w)*16;             // 32 j-tiles over 8 waves x 4 iters
    const int j  = j0 + hl;                  // A row
    const float* rf = relf + ((size_t)bi*512 + j)*64 + kc*8;
    const float4 x0 = *(const float4*)rf;
    const float4 x1 = *(const float4*)(rf + 4);
    const float4 y0 = *(const float4*)(rf + 32);
    const float4 y1 = *(const float4*)(rf + 36);
    const bf16x8 a0 = cvt8pk(x0, x1);
    const bf16x8 a1 = cvt8pk(y0, y1);
    f32x4 acc = {0.f, 0.f, 0.f, 0.f};
    acc = __builtin_amdgcn_mfma_f32_16x16x32_bf16(a0, b0, acc, 0, 0, 0);
    acc = __builtin_amdgcn_mfma_f32_16x16x32_bf16(a1, b1, acc, 0, 0, 0);
    if (hl < 8) {
      uint2 pk;
      pk.x = cvtpk(acc[0] + qbv, acc[1] + qbv);
      pk.y = cvtpk(acc[2] + qbv, acc[3] + qbv);
      *(uint2*)&Sp[j0 + kc*4] = pk;
    }
  }
}

// ---------------------------------------------------------------------------
// K3: per (bh, it=16 rows), 8 waves: base scores (MFMA) -> LDS;
//     softmax( 0.125*base + Sb ) -> Pt (bf16, pad 18); PV (bf16 V, fp32 acc)
// LDS: 33.0K (Ssm) + 18.4K (Pt) = 51.5K -> 3 blocks/CU (was 74K -> 2)
// ---------------------------------------------------------------------------
__global__ __launch_bounds__(512) void softmax_pv_kernel(
    const ushort_t* __restrict__ Sb, const ushort_t* __restrict__ srcb,
    float* __restrict__ attn_out)
{
  const int bh = blockIdx.x, it = blockIdx.y;
  const int b = bh >> 3, h = bh & 7;
  const int i0 = it * 16;
  const int tid = threadIdx.x;
  const int lane = tid & 63, w = tid >> 6;   // w 0..7
  __shared__ float Ssm[16][516];
  __shared__ ushort_t Pt[512*18];            // P transposed [j][i], bf16, pad 18

  // ---- Phase A: base scores Q.K^T via MFMA ----
  {
    const int il = lane & 15, kc = lane >> 4;
    const bf16x8 aq0 = *(const bf16x8*)&srcb[(size_t)(b*512 + i0 + il)*512 + h*64 + kc*8];
    const bf16x8 aq1 = *(const bf16x8*)&srcb[(size_t)(b*512 + i0 + il)*512 + h*64 + 32 + kc*8];
    #pragma unroll
    for (int t = 0; t < 4; ++t) {
      const int jt = t*8 + w;                // 0..31
      const int j  = jt*16 + il;             // B col
      const bf16x8 bk0 = *(const bf16x8*)&srcb[(size_t)(b*512 + j)*512 + h*64 + kc*8];
      const bf16x8 bk1 = *(const bf16x8*)&srcb[(size_t)(b*512 + j)*512 + h*64 + 32 + kc*8];
      f32x4 acc = {0.f, 0.f, 0.f, 0.f};
      acc = __builtin_amdgcn_mfma_f32_16x16x32_bf16(aq0, bk0, acc, 0, 0, 0);
      acc = __builtin_amdgcn_mfma_f32_16x16x32_bf16(aq1, bk1, acc, 0, 0, 0);
      #pragma unroll
      for (int r = 0; r < 4; ++r) Ssm[kc*4 + r][jt*16 + il] = acc[r];
    }
  }
  __syncthreads();

  // ---- Phase B: softmax rows (2 rows per wave) ----
  #pragma unroll
  for (int k = 0; k < 2; ++k) {
    const int row = w*2 + k;
    const ushort_t* Srow = Sb + ((size_t)(b*512 + i0 + row)*8 + h)*512;
    float v[8];
    float m = -1e30f;
    #pragma unroll
    for (int r = 0; r < 8; ++r) {
      v[r] = Ssm[row][lane + 64*r]*0.125f + bf2f(Srow[lane + 64*r]);
      m = fmaxf(m, v[r]);
    }
    #pragma unroll
    for (int o = 32; o > 0; o >>= 1) m = fmaxf(m, __shfl_xor(m, o, 64));
    float s = 0.f;
    #pragma unroll
    for (int r = 0; r < 8; ++r) { v[r] = __expf(v[r] - m); s += v[r]; }
    #pragma unroll
    for (int o = 32; o > 0; o >>= 1) s += __shfl_xor(s, o, 64);
    const float inv = 1.f / s;
    #pragma unroll
    for (int r = 0; r < 8; ++r) Pt[(lane + 64*r)*18 + row] = f2bf(v[r] * inv);
  }
  __syncthreads();

  // ---- Phase C: PV (bf16 V + bf16 P, fp32 acc), 2 i-rows per thread ----
  {
    const int d = lane, ig = w;
    const ushort_t* V = srcb + (size_t)(b*512)*512 + h*64 + d;
    float acc0=0.f, acc1=0.f;
    #pragma unroll 8
    for (int j = 0; j < 512; ++j) {
      const float vv = bf2f(V[(size_t)j*512]);
      const uint_t pk = *(const uint_t*)&Pt[j*18 + ig*2];   // broadcast, aligned
      acc0 = fmaf(bf2f((ushort_t)(pk & 0xFFFF)), vv, acc0);
      acc1 = fmaf(bf2f((ushort_t)(pk >> 16)),   vv, acc1);
    }
    float* out = attn_out + ((size_t)(b*512) + i0)*512 + h*64 + d;
    out[(size_t)(ig*2+0)*512] = acc0;
    out[(size_t)(ig*2+1)*512] = acc1;
  }
}

// ---------------------------------------------------------------------------
// K4: x = LN(src + attn_out) * g1 + be1 ; also emit x in bf16
// ---------------------------------------------------------------------------
__global__ __launch_bounds__(256) void ln1_kernel(
    const float* __restrict__ a, const float* __restrict__ bb,
    const float* __restrict__ g, const float* __restrict__ be,
    float* __restrict__ out, ushort_t* __restrict__ xb)
{
  const int bi = blockIdx.x, tid = threadIdx.x;
  const int d0 = tid * 2;
  const float2 xa = *(const float2*)&a [bi*512 + d0];
  const float2 xv = *(const float2*)&bb[bi*512 + d0];
  const float y0 = xa.x + xv.x;
  const float y1 = xa.y + xv.y;
  float s1 = y0 + y1, s2 = y0*y0 + y1*y1;
  #pragma unroll
  for (int o = 32; o > 0; o >>= 1) { s1 += __shfl_xor(s1, o, 64); s2 += __shfl_xor(s2, o, 64); }
  __shared__ float r1[4], r2[4];
  const int w = tid >> 6;
  if ((tid & 63) == 0) { r1[w] = s1; r2[w] = s2; }
  __syncthreads();
  const float t1 = r1[0] + r1[1] + r1[2] + r1[3];
  const float t2 = r2[0] + r2[1] + r2[2] + r2[3];
  const float mu  = t1 * (1.f/512.f);
  const float var = t2 * (1.f/512.f) - mu*mu;
  const float rs  = rsqrtf(var + LN_EPS);
  const float2 gg = *(const float2*)&g [d0];
  const float2 bv = *(const float2*)&be[d0];
  const float o0 = (y0 - mu)*rs*gg.x + bv.x;
  const float o1 = (y1 - mu)*rs*gg.y + bv.y;
  out[bi*512 + d0]     = o0;
  out[bi*512 + d0 + 1] = o1;
  *(uint_t*)&xb[bi*512 + d0] = cvtpk(o0, o1);
}

// ---------------------------------------------------------------------------
// K5: MFMA GEMM  ff = leaky_relu(xb @ w1b^T + b1), bf16 out
// BM=64 BN=64 BK=64; 4 waves 2x2, wave tile 32x32 (2x2 frags); grid (16,32)
// ---------------------------------------------------------------------------
__global__ __launch_bounds__(256) void gemm_ffn1(
    const ushort_t* __restrict__ A,   // [1024][512]
    const ushort_t* __restrict__ B,   // [2048][512]
    const float* __restrict__ bias, ushort_t* __restrict__ C)  // [1024][2048]
{
  __shared__ ushort_t Asm[64*64];
  __shared__ ushort_t Bsm[64*64];
  const int tid = threadIdx.x;
  const int m0 = blockIdx.x * 64, n0 = blockIdx.y * 64;
  const int lane = tid & 63;
  const int wr = (tid >> 7) & 1, wc = (tid >> 6) & 1;

  const int row = tid >> 2, r7 = row & 7;
  const int cb  = (tid & 3) * 2;

  f32x4 acc[2][2] = {};
  for (int kt = 0; kt < 8; ++kt) {
    const uint4* ga = (const uint4*)(A + (size_t)(m0 + row)*512 + kt*64);
    const uint4 av0 = ga[cb], av1 = ga[cb+1];
    const uint4* gb = (const uint4*)(B + (size_t)(n0 + row)*512 + kt*64);
    const uint4 bv0 = gb[cb], bv1 = gb[cb+1];
    __syncthreads();
    *(uint4*)&Asm[row*64 + (((cb+0) ^ r7) << 3)] = av0;
    *(uint4*)&Asm[row*64 + (((cb+1) ^ r7) << 3)] = av1;
    *(uint4*)&Bsm[row*64 + (((cb+0) ^ r7) << 3)] = bv0;
    *(uint4*)&Bsm[row*64 + (((cb+1) ^ r7) << 3)] = bv1;
    __syncthreads();
    #pragma unroll
    for (int kk = 0; kk < 2; ++kk) {
      bf16x8 af[2], bfm[2];
      #pragma unroll
      for (int fm = 0; fm < 2; ++fm) {
        const int r = wr*32 + fm*16 + (lane & 15);
        const int c = (kk*4 + (lane >> 4)) ^ (r & 7);
        af[fm] = *(const bf16x8*)&Asm[r*64 + c*8];
      }
      #pragma unroll
      for (int fn = 0; fn < 2; ++fn) {
        const int r = wc*32 + fn*16 + (lane & 15);
        const int c = (kk*4 + (lane >> 4)) ^ (r & 7);
        bfm[fn] = *(const bf16x8*)&Bsm[r*64 + c*8];
      }
      #pragma unroll
      for (int fm = 0; fm < 2; ++fm)
        #pragma unroll
        for (int fn = 0; fn < 2; ++fn)
          acc[fm][fn] = __builtin_amdgcn_mfma_f32_16x16x32_bf16(af[fm], bfm[fn], acc[fm][fn], 0, 0, 0);
    }
  }
  #pragma unroll
  for (int fn = 0; fn < 2; ++fn) {
    const int col = n0 + wc*32 + fn*16 + (lane & 15);
    const float bb = bias[col];
    #pragma unroll
    for (int fm = 0; fm < 2; ++fm) {
      #pragma unroll
      for (int r = 0; r < 4; ++r) {
        const int orow = m0 + wr*32 + fm*16 + (lane >> 4)*4 + r;
        float t = acc[fm][fn][r] + bb;
        t = t > 0.f ? t : 0.01f*t;
        C[(size_t)orow*2048 + col] = f2bf(t);
      }
    }
  }
}

// ---------------------------------------------------------------------------
// K6: MFMA GEMM  p[z] = ff @ w2b^T over K-slice z*256..+256, fp32 partials
// BM=64 BN=64; grid (16, 8, 8) = 1024 blocks (4/CU)
// ---------------------------------------------------------------------------
__global__ __launch_bounds__(256) void gemm_ffn2(
    const ushort_t* __restrict__ A,   // ff [1024][2048]
    const ushort_t* __restrict__ B,   // w2b [512][2048]
    float* __restrict__ P)            // [8][1024][512]
{
  __shared__ ushort_t Asm[64*64];
  __shared__ ushort_t Bsm[64*64];
  const int tid = threadIdx.x;
  const int m0 = blockIdx.x * 64, n0 = blockIdx.y * 64;
  const int kbase = blockIdx.z * 256;
  float* outp = P + (size_t)blockIdx.z * 524288;
  const int lane = tid & 63;
  const int wr = (tid >> 7) & 1, wc = (tid >> 6) & 1;

  const int row = tid >> 2, r7 = row & 7;
  const int cb  = (tid & 3) * 2;

  f32x4 acc[2][2] = {};
  for (int kt = 0; kt < 4; ++kt) {
    const uint4* ga = (const uint4*)(A + (size_t)(m0 + row)*2048 + kbase + kt*64);
    const uint4 av0 = ga[cb], av1 = ga[cb+1];
    const uint4* gb = (const uint4*)(B + (size_t)(n0 + row)*2048 + kbase + kt*64);
    const uint4 bv0 = gb[cb], bv1 = gb[cb+1];
    __syncthreads();
    *(uint4*)&Asm[row*64 + (((cb+0) ^ r7) << 3)] = av0;
    *(uint4*)&Asm[row*64 + (((cb+1) ^ r7) << 3)] = av1;
    *(uint4*)&Bsm[row*64 + (((cb+0) ^ r7) << 3)] = bv0;
    *(uint4*)&Bsm[row*64 + (((cb+1) ^ r7) << 3)] = bv1;
    __syncthreads();
    #pragma unroll
    for (int kk = 0; kk < 2; ++kk) {
      bf16x8 af[2], bfm[2];
      #pragma unroll
      for (int fm = 0; fm < 2; ++fm) {
        const int r = wr*32 + fm*16 + (lane & 15);
        const int c = (kk*4 + (lane >> 4)) ^ (r & 7);
        af[fm] = *(const bf16x8*)&Asm[r*64 + c*8];
      }
      #pragma unroll
      for (int fn = 0; fn < 2; ++fn) {
        const int r = wc*32 + fn*16 + (lane & 15);
        const int c = (kk*4 + (lane >> 4)) ^ (r & 7);
        bfm[fn] = *(const bf16x8*)&Bsm[r*64 + c*8];
      }
      #pragma unroll
      for (int fm = 0; fm < 2; ++fm)
        #pragma unroll
        for (int fn = 0; fn < 2; ++fn)
          acc[fm][fn] = __builtin_amdgcn_mfma_f32_16x16x32_bf16(af[fm], bfm[fn], acc[fm][fn], 0, 0, 0);
    }
  }
  #pragma unroll
  for (int fn = 0; fn < 2; ++fn) {
    const int col = n0 + wc*32 + fn*16 + (lane & 15);
    #pragma unroll
    for (int fm = 0; fm < 2; ++fm) {
      #pragma unroll
      for (int r = 0; r < 4; ++r) {
        const int orow = m0 + wr*32 + fm*16 + (lane >> 4)*4 + r;
        outp[(size_t)orow*512 + col] = acc[fm][fn][r];
      }
    }
  }
}

// ---------------------------------------------------------------------------
// K7: out = LN(x + sum_{z<8} p[z] + b2) * g2 + be2
// ---------------------------------------------------------------------------
__global__ __launch_bounds__(256) void ln2_kernel(
    const float* __restrict__ p, const float* __restrict__ x,
    const float* __restrict__ b2, const float* __restrict__ g2,
    const float* __restrict__ be2, float* __restrict__ out)
{
  const int bi = blockIdx.x, tid = threadIdx.x;
  const int d0 = tid * 2;
  float y0 = 0.f, y1 = 0.f;
  #pragma unroll
  for (int z = 0; z < 8; ++z) {
    const float2 a = *(const float2*)&p[(size_t)z*524288 + bi*512 + d0];
    y0 += a.x; y1 += a.y;
  }
  const float2 xr = *(const float2*)&x [bi*512 + d0];
  const float2 bb = *(const float2*)&b2[d0];
  y0 += bb.x + xr.x;
  y1 += bb.y + xr.y;
  float s1 = y0 + y1, s2 = y0*y0 + y1*y1;
  #pragma unroll
  for (int o = 32; o > 0; o >>= 1) { s1 += __shfl_xor(s1, o, 64); s2 += __shfl_xor(s2, o, 64); }
  __shared__ float r1[4], r2[4];
  const int w = tid >> 6;
  if ((tid & 63) == 0) { r1[w] = s1; r2[w] = s2; }
  __syncthreads();
  const float t1 = r1[0] + r1[1] + r1[2] + r1[3];
  const float t2 = r2[0] + r2[1] + r2[2] + r2[3];
  const float mu  = t1 * (1.f/512.f);
  const float var = t2 * (1.f/512.f) - mu*mu;
  const float rs  = rsqrtf(var + LN_EPS);
  const float2 g  = *(const float2*)&g2 [d0];
  const float2 be = *(const float2*)&be2[d0];
  out[bi*512 + d0]     = (y0 - mu)*rs*g.x + be.x;
  out[bi*512 + d0 + 1] = (y1 - mu)*rs*g.y + be.y;
}

// ---------------------------------------------------------------------------
extern "C" void kernel_launch(void* const* d_in, const int* in_sizes, int n_in,
                              void* d_out, int out_size, void* d_ws, size_t ws_size,
                              hipStream_t stream) {
  const float* src  = (const float*)d_in[0];
  const float* relf = (const float*)d_in[1];
  const float* rel_w = (const float*)d_in[2];
  const float* rel_b = (const float*)d_in[3];
  const float* w1 = (const float*)d_in[4];
  const float* b1 = (const float*)d_in[5];
  const float* w2 = (const float*)d_in[6];
  const float* b2 = (const float*)d_in[7];
  const float* g1  = (const float*)d_in[8];
  const float* be1 = (const float*)d_in[9];
  const float* g2  = (const float*)d_in[10];
  const float* be2 = (const float*)d_in[11];
  float* out = (float*)d_out;

  float* ws = (float*)d_ws;
  ushort_t* qwb  = (ushort_t*)(ws);                 // 524288 bf16
  float*    qb   = ws + 262144;                     // 8192 f
  ushort_t* srcb = (ushort_t*)(ws + 270336);        // 524288 bf16
  ushort_t* Sb   = (ushort_t*)(ws + 532480);        // 4194304 bf16
  float*    attn = ws + 2629632;                    // 524288 f
  float*    x    = ws + 3153920;                    // 524288 f
  ushort_t* xb   = (ushort_t*)(ws + 3678208);       // 524288 bf16
  ushort_t* w1b  = (ushort_t*)(ws + 3940352);       // 1048576 bf16
  ushort_t* w2b  = (ushort_t*)(ws + 4464640);       // 1048576 bf16
  ushort_t* ffb  = (ushort_t*)(ws + 4988928);       // 2097152 bf16
  float*    p    = ws + 6037504;                    // 8 x 524288 f

  qw_conv_kernel   <<<1152, 256, 0, stream>>>(src, rel_w, rel_b, w1, w2,
                                              qwb, qb, srcb, w1b, w2b);
  rel_stream_kernel<<<1024, 512, 0, stream>>>(relf, qwb, qb, Sb);
  softmax_pv_kernel<<<dim3(16, 32), 512, 0, stream>>>(Sb, srcb, attn);
  ln1_kernel       <<<1024, 256, 0, stream>>>(src, attn, g1, be1, x, xb);
  gemm_ffn1        <<<dim3(16, 32), 256, 0, stream>>>(xb, w1b, b1, ffb);
  gemm_ffn2        <<<dim3(16, 8, 8), 256, 0, stream>>>(ffb, w2b, p);
  ln2_kernel       <<<1024, 256, 0, stream>>>(p, x, b2, g2, be2, out);
}

// Round 15
// 82.486 us; speedup vs baseline: 1.0806x; 1.0806x over previous
//
#include <hip/hip_runtime.h>
#include <math.h>

#define LN_EPS 1e-5f
// B=2 L=512 D=512 H=8 DH=64 C=64 F=2048
// Sb layout (bf16): Sb[b,i,h,j] = Sb[((b*512+i)*8 + h)*512 + j]

typedef __bf16 bf16x8 __attribute__((ext_vector_type(8)));
typedef unsigned short u16x8 __attribute__((ext_vector_type(8)));
typedef float f32x4 __attribute__((ext_vector_type(4)));
typedef unsigned short ushort_t;
typedef unsigned int uint_t;

__device__ inline ushort_t f2bf(float f) {
  uint_t u = __float_as_uint(f);
  return (ushort_t)((u + 0x7FFFu + ((u >> 16) & 1u)) >> 16);
}
__device__ inline float bf2f(ushort_t b) {
  return __uint_as_float(((uint_t)b) << 16);
}
// v_cvt_pk_bf16_f32: D[15:0]=bf16(S0), D[31:16]=bf16(S1)
__device__ inline uint_t cvtpk(float lo, float hi) {
  uint_t r;
  asm("v_cvt_pk_bf16_f32 %0, %1, %2" : "=v"(r) : "v"(lo), "v"(hi));
  return r;
}
__device__ inline bf16x8 cvt8pk(float4 a, float4 b) {
  uint4 v;
  v.x = cvtpk(a.x, a.y); v.y = cvtpk(a.z, a.w);
  v.z = cvtpk(b.x, b.y); v.w = cvtpk(b.z, b.w);
  return __builtin_bit_cast(bf16x8, v);
}

// ---------------------------------------------------------------------------
// K1 "qw_conv": blocks 0..1023: qwb[b,i,h,c] (bf16, coalesced rel_w reads),
//   qb[b,i,h], and srcb row (src row already staged in LDS).
// blocks 1024..1151: convert w1->w1b, w2->w2b.
// ---------------------------------------------------------------------------
__global__ __launch_bounds__(256) void qw_conv_kernel(
    const float* __restrict__ src, const float* __restrict__ rel_w,
    const float* __restrict__ rel_b,
    const float* __restrict__ w1, const float* __restrict__ w2,
    ushort_t* __restrict__ qwb, float* __restrict__ qb,
    ushort_t* __restrict__ srcb, ushort_t* __restrict__ w1b,
    ushort_t* __restrict__ w2b)
{
  const int tid = threadIdx.x;
  if (blockIdx.x >= 1024) {
    const int cb = blockIdx.x - 1024;          // 0..127
    const int tg = cb*256 + tid;               // 0..32767
    for (int it = tg; it < 131072; it += 32768) {
      const int i = it*8;
      const float4 a = *(const float4*)(w1 + i);
      const float4 b = *(const float4*)(w1 + i + 4);
      uint4 v;
      v.x = cvtpk(a.x, a.y); v.y = cvtpk(a.z, a.w);
      v.z = cvtpk(b.x, b.y); v.w = cvtpk(b.z, b.w);
      *(uint4*)(w1b + i) = v;
    }
    for (int it = tg; it < 131072; it += 32768) {
      const int i = it*8;
      const float4 a = *(const float4*)(w2 + i);
      const float4 b = *(const float4*)(w2 + i + 4);
      uint4 v;
      v.x = cvtpk(a.x, a.y); v.y = cvtpk(a.z, a.w);
      v.z = cvtpk(b.x, b.y); v.w = cvtpk(b.z, b.w);
      *(uint4*)(w2b + i) = v;
    }
    return;
  }

  const int bi = blockIdx.x;     // b*512 + i
  __shared__ float q_sh[512];
  q_sh[tid]       = src[bi*512 + tid];
  q_sh[tid + 256] = src[bi*512 + tid + 256];
  __syncthreads();
  // srcb from LDS
  {
    const float a = q_sh[2*tid], b = q_sh[2*tid + 1];
    *(uint_t*)&srcb[(size_t)bi*512 + 2*tid] = cvtpk(a, b);
  }
  // qw: wave w owns heads {2w, 2w+1}; lane = c. rel_w reads coalesced per d.
  const int lane = tid & 63, w = tid >> 6;
  #pragma unroll
  for (int hh = 0; hh < 2; ++hh) {
    const int h = w*2 + hh;
    const float* rwh = rel_w + h*4096;      // rel_w[(h*64+d)*64 + c]
    float s = 0.f;
    #pragma unroll 8
    for (int d = 0; d < 64; ++d)
      s = fmaf(q_sh[h*64 + d], rwh[d*64 + lane], s);
    qwb[(size_t)bi*512 + h*64 + lane] = f2bf(s);
  }
  if (tid < 8) {
    float s = 0.f;
    for (int d = 0; d < 64; ++d) s = fmaf(q_sh[tid*64+d], rel_b[tid*64+d], s);
    qb[bi*8 + tid] = s;
  }
}

// ---------------------------------------------------------------------------
// K2 "rel_stream": pure 134MB stream, 8 waves/block:
//   Sb[b,i,h,j] = bf16( sum_c RF[b,i,j,c]*qw[h,c] + qb[h] ) via MFMA.
// ---------------------------------------------------------------------------
__global__ __launch_bounds__(512) void rel_stream_kernel(
    const float* __restrict__ relf, const ushort_t* __restrict__ qwb,
    const float* __restrict__ qb, ushort_t* __restrict__ Sb)
{
  const int bi = blockIdx.x;           // b*512 + i
  const int tid = threadIdx.x;
  const int lane = tid & 63, w = tid >> 6;   // w 0..7
  const int hl = lane & 15;          // D col (head), valid < 8
  const int kc = lane >> 4;          // k-chunk 0..3
  const int h  = hl & 7;

  const bf16x8 b0 = *(const bf16x8*)&qwb[(size_t)bi*512 + h*64 + kc*8];
  const bf16x8 b1 = *(const bf16x8*)&qwb[(size_t)bi*512 + h*64 + 32 + kc*8];
  const float qbv = qb[bi*8 + h];
  ushort_t* Sp = Sb + ((size_t)bi*8 + h)*512;

  #pragma unroll
  for (int t = 0; t < 4; ++t) {
    const int j0 = (t*8 + w)*16;             // 32 j-tiles over 8 waves x 4 iters
    const int j  = j0 + hl;                  // A row
    const float* rf = relf + ((size_t)bi*512 + j)*64 + kc*8;
    const float4 x0 = *(const float4*)rf;
    const float4 x1 = *(const float4*)(rf + 4);
    const float4 y0 = *(const float4*)(rf + 32);
    const float4 y1 = *(const float4*)(rf + 36);
    const bf16x8 a0 = cvt8pk(x0, x1);
    const bf16x8 a1 = cvt8pk(y0, y1);
    f32x4 acc = {0.f, 0.f, 0.f, 0.f};
    acc = __builtin_amdgcn_mfma_f32_16x16x32_bf16(a0, b0, acc, 0, 0, 0);
    acc = __builtin_amdgcn_mfma_f32_16x16x32_bf16(a1, b1, acc, 0, 0, 0);
    if (hl < 8) {
      uint2 pk;
      pk.x = cvtpk(acc[0] + qbv, acc[1] + qbv);
      pk.y = cvtpk(acc[2] + qbv, acc[3] + qbv);
      *(uint2*)&Sp[j0 + kc*4] = pk;
    }
  }
}

// ---------------------------------------------------------------------------
// K3: per (bh, it=16 rows), 8 waves: base scores (MFMA) -> LDS;
//     softmax( 0.125*base + Sb ) -> Pt; PV (bf16 V, fp32 acc) -> attn_out
// ---------------------------------------------------------------------------
__global__ __launch_bounds__(512) void softmax_pv_kernel(
    const ushort_t* __restrict__ Sb, const ushort_t* __restrict__ srcb,
    float* __restrict__ attn_out)
{
  const int bh = blockIdx.x, it = blockIdx.y;
  const int b = bh >> 3, h = bh & 7;
  const int i0 = it * 16;
  const int tid = threadIdx.x;
  const int lane = tid & 63, w = tid >> 6;   // w 0..7
  __shared__ float Ssm[16][516];
  __shared__ float Pt[512*20];

  // ---- Phase A: base scores Q.K^T via MFMA ----
  {
    const int il = lane & 15, kc = lane >> 4;
    const bf16x8 aq0 = *(const bf16x8*)&srcb[(size_t)(b*512 + i0 + il)*512 + h*64 + kc*8];
    const bf16x8 aq1 = *(const bf16x8*)&srcb[(size_t)(b*512 + i0 + il)*512 + h*64 + 32 + kc*8];
    #pragma unroll
    for (int t = 0; t < 4; ++t) {
      const int jt = t*8 + w;                // 0..31
      const int j  = jt*16 + il;             // B col
      const bf16x8 bk0 = *(const bf16x8*)&srcb[(size_t)(b*512 + j)*512 + h*64 + kc*8];
      const bf16x8 bk1 = *(const bf16x8*)&srcb[(size_t)(b*512 + j)*512 + h*64 + 32 + kc*8];
      f32x4 acc = {0.f, 0.f, 0.f, 0.f};
      acc = __builtin_amdgcn_mfma_f32_16x16x32_bf16(aq0, bk0, acc, 0, 0, 0);
      acc = __builtin_amdgcn_mfma_f32_16x16x32_bf16(aq1, bk1, acc, 0, 0, 0);
      #pragma unroll
      for (int r = 0; r < 4; ++r) Ssm[kc*4 + r][jt*16 + il] = acc[r];
    }
  }
  __syncthreads();

  // ---- Phase B: softmax rows (2 rows per wave) ----
  #pragma unroll
  for (int k = 0; k < 2; ++k) {
    const int row = w*2 + k;
    const ushort_t* Srow = Sb + ((size_t)(b*512 + i0 + row)*8 + h)*512;
    float v[8];
    float m = -1e30f;
    #pragma unroll
    for (int r = 0; r < 8; ++r) {
      v[r] = Ssm[row][lane + 64*r]*0.125f + bf2f(Srow[lane + 64*r]);
      m = fmaxf(m, v[r]);
    }
    #pragma unroll
    for (int o = 32; o > 0; o >>= 1) m = fmaxf(m, __shfl_xor(m, o, 64));
    float s = 0.f;
    #pragma unroll
    for (int r = 0; r < 8; ++r) { v[r] = __expf(v[r] - m); s += v[r]; }
    #pragma unroll
    for (int o = 32; o > 0; o >>= 1) s += __shfl_xor(s, o, 64);
    const float inv = 1.f / s;
    #pragma unroll
    for (int r = 0; r < 8; ++r) Pt[(lane + 64*r)*20 + row] = v[r] * inv;
  }
  __syncthreads();

  // ---- Phase C: PV (bf16 V, fp32 acc), 2 i-rows per thread ----
  {
    const int d = lane, ig = w;
    const ushort_t* V = srcb + (size_t)(b*512)*512 + h*64 + d;
    float acc0=0.f, acc1=0.f;
    #pragma unroll 8
    for (int j = 0; j < 512; ++j) {
      const float vv = bf2f(V[(size_t)j*512]);
      const float2 p = *(const float2*)&Pt[j*20 + ig*2];
      acc0 = fmaf(p.x, vv, acc0); acc1 = fmaf(p.y, vv, acc1);
    }
    float* out = attn_out + ((size_t)(b*512) + i0)*512 + h*64 + d;
    out[(size_t)(ig*2+0)*512] = acc0;
    out[(size_t)(ig*2+1)*512] = acc1;
  }
}

// ---------------------------------------------------------------------------
// K4: x = LN(src + attn_out) * g1 + be1 ; also emit x in bf16
// ---------------------------------------------------------------------------
__global__ __launch_bounds__(256) void ln1_kernel(
    const float* __restrict__ a, const float* __restrict__ bb,
    const float* __restrict__ g, const float* __restrict__ be,
    float* __restrict__ out, ushort_t* __restrict__ xb)
{
  const int bi = blockIdx.x, tid = threadIdx.x;
  const int d0 = tid * 2;
  const float2 xa = *(const float2*)&a [bi*512 + d0];
  const float2 xv = *(const float2*)&bb[bi*512 + d0];
  const float y0 = xa.x + xv.x;
  const float y1 = xa.y + xv.y;
  float s1 = y0 + y1, s2 = y0*y0 + y1*y1;
  #pragma unroll
  for (int o = 32; o > 0; o >>= 1) { s1 += __shfl_xor(s1, o, 64); s2 += __shfl_xor(s2, o, 64); }
  __shared__ float r1[4], r2[4];
  const int w = tid >> 6;
  if ((tid & 63) == 0) { r1[w] = s1; r2[w] = s2; }
  __syncthreads();
  const float t1 = r1[0] + r1[1] + r1[2] + r1[3];
  const float t2 = r2[0] + r2[1] + r2[2] + r2[3];
  const float mu  = t1 * (1.f/512.f);
  const float var = t2 * (1.f/512.f) - mu*mu;
  const float rs  = rsqrtf(var + LN_EPS);
  const float2 gg = *(const float2*)&g [d0];
  const float2 bv = *(const float2*)&be[d0];
  const float o0 = (y0 - mu)*rs*gg.x + bv.x;
  const float o1 = (y1 - mu)*rs*gg.y + bv.y;
  out[bi*512 + d0]     = o0;
  out[bi*512 + d0 + 1] = o1;
  *(uint_t*)&xb[bi*512 + d0] = cvtpk(o0, o1);
}

// ---------------------------------------------------------------------------
// K5: MFMA GEMM  ff = leaky_relu(xb @ w1b^T + b1), bf16 out
// BM=64 BN=64 BK=64; 4 waves 2x2, wave tile 32x32 (2x2 frags); grid (16,32)
// ---------------------------------------------------------------------------
__global__ __launch_bounds__(256) void gemm_ffn1(
    const ushort_t* __restrict__ A,   // [1024][512]
    const ushort_t* __restrict__ B,   // [2048][512]
    const float* __restrict__ bias, ushort_t* __restrict__ C)  // [1024][2048]
{
  __shared__ ushort_t Asm[64*64];
  __shared__ ushort_t Bsm[64*64];
  const int tid = threadIdx.x;
  const int m0 = blockIdx.x * 64, n0 = blockIdx.y * 64;
  const int lane = tid & 63;
  const int wr = (tid >> 7) & 1, wc = (tid >> 6) & 1;

  const int row = tid >> 2, r7 = row & 7;
  const int cb  = (tid & 3) * 2;

  f32x4 acc[2][2] = {};
  for (int kt = 0; kt < 8; ++kt) {
    const uint4* ga = (const uint4*)(A + (size_t)(m0 + row)*512 + kt*64);
    const uint4 av0 = ga[cb], av1 = ga[cb+1];
    const uint4* gb = (const uint4*)(B + (size_t)(n0 + row)*512 + kt*64);
    const uint4 bv0 = gb[cb], bv1 = gb[cb+1];
    __syncthreads();
    *(uint4*)&Asm[row*64 + (((cb+0) ^ r7) << 3)] = av0;
    *(uint4*)&Asm[row*64 + (((cb+1) ^ r7) << 3)] = av1;
    *(uint4*)&Bsm[row*64 + (((cb+0) ^ r7) << 3)] = bv0;
    *(uint4*)&Bsm[row*64 + (((cb+1) ^ r7) << 3)] = bv1;
    __syncthreads();
    #pragma unroll
    for (int kk = 0; kk < 2; ++kk) {
      bf16x8 af[2], bfm[2];
      #pragma unroll
      for (int fm = 0; fm < 2; ++fm) {
        const int r = wr*32 + fm*16 + (lane & 15);
        const int c = (kk*4 + (lane >> 4)) ^ (r & 7);
        af[fm] = *(const bf16x8*)&Asm[r*64 + c*8];
      }
      #pragma unroll
      for (int fn = 0; fn < 2; ++fn) {
        const int r = wc*32 + fn*16 + (lane & 15);
        const int c = (kk*4 + (lane >> 4)) ^ (r & 7);
        bfm[fn] = *(const bf16x8*)&Bsm[r*64 + c*8];
      }
      #pragma unroll
      for (int fm = 0; fm < 2; ++fm)
        #pragma unroll
        for (int fn = 0; fn < 2; ++fn)
          acc[fm][fn] = __builtin_amdgcn_mfma_f32_16x16x32_bf16(af[fm], bfm[fn], acc[fm][fn], 0, 0, 0);
    }
  }
  #pragma unroll
  for (int fn = 0; fn < 2; ++fn) {
    const int col = n0 + wc*32 + fn*16 + (lane & 15);
    const float bb = bias[col];
    #pragma unroll
    for (int fm = 0; fm < 2; ++fm) {
      #pragma unroll
      for (int r = 0; r < 4; ++r) {
        const int orow = m0 + wr*32 + fm*16 + (lane >> 4)*4 + r;
        float t = acc[fm][fn][r] + bb;
        t = t > 0.f ? t : 0.01f*t;
        C[(size_t)orow*2048 + col] = f2bf(t);
      }
    }
  }
}

// ---------------------------------------------------------------------------
// K6: MFMA GEMM  p[z] = ff @ w2b^T over K-slice z*512..+512, fp32 partials
// BM=64 BN=64; grid (16, 8, 4)
// ---------------------------------------------------------------------------
__global__ __launch_bounds__(256) void gemm_ffn2(
    const ushort_t* __restrict__ A,   // ff [1024][2048]
    const ushort_t* __restrict__ B,   // w2b [512][2048]
    float* __restrict__ P)            // [4][1024][512]
{
  __shared__ ushort_t Asm[64*64];
  __shared__ ushort_t Bsm[64*64];
  const int tid = threadIdx.x;
  const int m0 = blockIdx.x * 64, n0 = blockIdx.y * 64;
  const int kbase = blockIdx.z * 512;
  float* outp = P + (size_t)blockIdx.z * 524288;
  const int lane = tid & 63;
  const int wr = (tid >> 7) & 1, wc = (tid >> 6) & 1;

  const int row = tid >> 2, r7 = row & 7;
  const int cb  = (tid & 3) * 2;

  f32x4 acc[2][2] = {};
  for (int kt = 0; kt < 8; ++kt) {
    const uint4* ga = (const uint4*)(A + (size_t)(m0 + row)*2048 + kbase + kt*64);
    const uint4 av0 = ga[cb], av1 = ga[cb+1];
    const uint4* gb = (const uint4*)(B + (size_t)(n0 + row)*2048 + kbase + kt*64);
    const uint4 bv0 = gb[cb], bv1 = gb[cb+1];
    __syncthreads();
    *(uint4*)&Asm[row*64 + (((cb+0) ^ r7) << 3)] = av0;
    *(uint4*)&Asm[row*64 + (((cb+1) ^ r7) << 3)] = av1;
    *(uint4*)&Bsm[row*64 + (((cb+0) ^ r7) << 3)] = bv0;
    *(uint4*)&Bsm[row*64 + (((cb+1) ^ r7) << 3)] = bv1;
    __syncthreads();
    #pragma unroll
    for (int kk = 0; kk < 2; ++kk) {
      bf16x8 af[2], bfm[2];
      #pragma unroll
      for (int fm = 0; fm < 2; ++fm) {
        const int r = wr*32 + fm*16 + (lane & 15);
        const int c = (kk*4 + (lane >> 4)) ^ (r & 7);
        af[fm] = *(const bf16x8*)&Asm[r*64 + c*8];
      }
      #pragma unroll
      for (int fn = 0; fn < 2; ++fn) {
        const int r = wc*32 + fn*16 + (lane & 15);
        const int c = (kk*4 + (lane >> 4)) ^ (r & 7);
        bfm[fn] = *(const bf16x8*)&Bsm[r*64 + c*8];
      }
      #pragma unroll
      for (int fm = 0; fm < 2; ++fm)
        #pragma unroll
        for (int fn = 0; fn < 2; ++fn)
          acc[fm][fn] = __builtin_amdgcn_mfma_f32_16x16x32_bf16(af[fm], bfm[fn], acc[fm][fn], 0, 0, 0);
    }
  }
  #pragma unroll
  for (int fn = 0; fn < 2; ++fn) {
    const int col = n0 + wc*32 + fn*16 + (lane & 15);
    #pragma unroll
    for (int fm = 0; fm < 2; ++fm) {
      #pragma unroll
      for (int r = 0; r < 4; ++r) {
        const int orow = m0 + wr*32 + fm*16 + (lane >> 4)*4 + r;
        outp[(size_t)orow*512 + col] = acc[fm][fn][r];
      }
    }
  }
}

// ---------------------------------------------------------------------------
// K7: out = LN(x + p0+p1+p2+p3 + b2) * g2 + be2
// ---------------------------------------------------------------------------
__global__ __launch_bounds__(256) void ln2_kernel(
    const float* __restrict__ p, const float* __restrict__ x,
    const float* __restrict__ b2, const float* __restrict__ g2,
    const float* __restrict__ be2, float* __restrict__ out)
{
  const int bi = blockIdx.x, tid = threadIdx.x;
  const int d0 = tid * 2;
  const float2 a0 = *(const float2*)&p[bi*512 + d0];
  const float2 a1 = *(const float2*)&p[524288 + bi*512 + d0];
  const float2 a2 = *(const float2*)&p[1048576 + bi*512 + d0];
  const float2 a3 = *(const float2*)&p[1572864 + bi*512 + d0];
  const float2 xr = *(const float2*)&x [bi*512 + d0];
  const float2 bb = *(const float2*)&b2[d0];
  const float y0 = a0.x + a1.x + a2.x + a3.x + bb.x + xr.x;
  const float y1 = a0.y + a1.y + a2.y + a3.y + bb.y + xr.y;
  float s1 = y0 + y1, s2 = y0*y0 + y1*y1;
  #pragma unroll
  for (int o = 32; o > 0; o >>= 1) { s1 += __shfl_xor(s1, o, 64); s2 += __shfl_xor(s2, o, 64); }
  __shared__ float r1[4], r2[4];
  const int w = tid >> 6;
  if ((tid & 63) == 0) { r1[w] = s1; r2[w] = s2; }
  __syncthreads();
  const float t1 = r1[0] + r1[1] + r1[2] + r1[3];
  const float t2 = r2[0] + r2[1] + r2[2] + r2[3];
  const float mu  = t1 * (1.f/512.f);
  const float var = t2 * (1.f/512.f) - mu*mu;
  const float rs  = rsqrtf(var + LN_EPS);
  const float2 g  = *(const float2*)&g2 [d0];
  const float2 be = *(const float2*)&be2[d0];
  out[bi*512 + d0]     = (y0 - mu)*rs*g.x + be.x;
  out[bi*512 + d0 + 1] = (y1 - mu)*rs*g.y + be.y;
}

// ---------------------------------------------------------------------------
extern "C" void kernel_launch(void* const* d_in, const int* in_sizes, int n_in,
                              void* d_out, int out_size, void* d_ws, size_t ws_size,
                              hipStream_t stream) {
  const float* src  = (const float*)d_in[0];
  const float* relf = (const float*)d_in[1];
  const float* rel_w = (const float*)d_in[2];
  const float* rel_b = (const float*)d_in[3];
  const float* w1 = (const float*)d_in[4];
  const float* b1 = (const float*)d_in[5];
  const float* w2 = (const float*)d_in[6];
  const float* b2 = (const float*)d_in[7];
  const float* g1  = (const float*)d_in[8];
  const float* be1 = (const float*)d_in[9];
  const float* g2  = (const float*)d_in[10];
  const float* be2 = (const float*)d_in[11];
  float* out = (float*)d_out;

  float* ws = (float*)d_ws;
  ushort_t* qwb  = (ushort_t*)(ws);                 // 524288 bf16
  float*    qb   = ws + 262144;                     // 8192 f
  ushort_t* srcb = (ushort_t*)(ws + 270336);        // 524288 bf16
  ushort_t* Sb   = (ushort_t*)(ws + 532480);        // 4194304 bf16
  float*    attn = ws + 2629632;                    // 524288 f
  float*    x    = ws + 3153920;                    // 524288 f
  ushort_t* xb   = (ushort_t*)(ws + 3678208);       // 524288 bf16
  ushort_t* w1b  = (ushort_t*)(ws + 3940352);       // 1048576 bf16
  ushort_t* w2b  = (ushort_t*)(ws + 4464640);       // 1048576 bf16
  ushort_t* ffb  = (ushort_t*)(ws + 4988928);       // 2097152 bf16
  float*    p    = ws + 6037504;                    // 2097152 f

  qw_conv_kernel   <<<1152, 256, 0, stream>>>(src, rel_w, rel_b, w1, w2,
                                              qwb, qb, srcb, w1b, w2b);
  rel_stream_kernel<<<1024, 512, 0, stream>>>(relf, qwb, qb, Sb);
  softmax_pv_kernel<<<dim3(16, 32), 512, 0, stream>>>(Sb, srcb, attn);
  ln1_kernel       <<<1024, 256, 0, stream>>>(src, attn, g1, be1, x, xb);
  gemm_ffn1        <<<dim3(16, 32), 256, 0, stream>>>(xb, w1b, b1, ffb);
  gemm_ffn2        <<<dim3(16, 8, 4), 256, 0, stream>>>(ffb, w2b, p);
  ln2_kernel       <<<1024, 256, 0, stream>>>(p, x, b2, g2, be2, out);
}